// Round 1
// baseline (2662.270 us; speedup 1.0000x reference)
//
#include <hip/hip_runtime.h>
#include <math.h>

typedef float f32x4 __attribute__((ext_vector_type(4)));
typedef unsigned short u16x8 __attribute__((ext_vector_type(8)));
typedef unsigned short u16x4 __attribute__((ext_vector_type(4)));
typedef __bf16 bf16x8 __attribute__((ext_vector_type(8)));

#define DEV static __device__ __forceinline__

DEV unsigned short f2bf(float f) {            // RNE f32 -> bf16 bits
  unsigned u = __float_as_uint(f);
  u += 0x7FFFu + ((u >> 16) & 1u);
  return (unsigned short)(u >> 16);
}
DEV float bf2f(unsigned short s) { return __uint_as_float(((unsigned)s) << 16); }
DEV bf16x8 asbf(u16x8 v) { return __builtin_bit_cast(bf16x8, v); }

// ---------------------------------------------------------------- embed
__global__ void embed_kernel(const int* __restrict__ x, const float* __restrict__ tok,
                             const float* __restrict__ pos, float* __restrict__ h,
                             unsigned short* __restrict__ hbf) {
  int t = blockIdx.x, tid = threadIdx.x;
  int v = x[t], s = t & 1023;                 // S = 1024
  f32x4 a = *(const f32x4*)(tok + (size_t)v * 1024 + tid * 4);
  f32x4 b = *(const f32x4*)(pos + (size_t)s * 1024 + tid * 4);
  f32x4 r = a + b;
  *(f32x4*)(h + (size_t)t * 1024 + tid * 4) = r;
  u16x4 rb;
  for (int i = 0; i < 4; ++i) rb[i] = f2bf(r[i]);
  *(u16x4*)(hbf + (size_t)t * 1024 + tid * 4) = rb;
}

// ---------------------------------------------------------------- LayerNorm(pre + res)
__global__ __launch_bounds__(256) void ln_kernel(const float* __restrict__ pre,
    const float* __restrict__ res, const float* __restrict__ g, const float* __restrict__ bta,
    float* __restrict__ outf, unsigned short* __restrict__ outbf) {
  int row = blockIdx.x, tid = threadIdx.x;
  size_t base = (size_t)row * 1024 + tid * 4;
  f32x4 xv = *(const f32x4*)(pre + base);
  f32x4 rv = *(const f32x4*)(res + base);
  xv += rv;
  float s = xv[0] + xv[1] + xv[2] + xv[3];
  float s2 = xv[0]*xv[0] + xv[1]*xv[1] + xv[2]*xv[2] + xv[3]*xv[3];
  for (int m = 1; m < 64; m <<= 1) { s += __shfl_xor(s, m); s2 += __shfl_xor(s2, m); }
  __shared__ float red[8];
  int w = tid >> 6;
  if ((tid & 63) == 0) { red[w * 2] = s; red[w * 2 + 1] = s2; }
  __syncthreads();
  s = red[0] + red[2] + red[4] + red[6];
  s2 = red[1] + red[3] + red[5] + red[7];
  float mu = s * (1.f / 1024.f);
  float var = s2 * (1.f / 1024.f) - mu * mu;
  float rs = rsqrtf(var + 1e-5f);
  f32x4 gv = *(const f32x4*)(g + tid * 4);
  f32x4 bv = *(const f32x4*)(bta + tid * 4);
  f32x4 o; u16x4 ob;
  for (int i = 0; i < 4; ++i) { o[i] = (xv[i] - mu) * rs * gv[i] + bv[i]; ob[i] = f2bf(o[i]); }
  *(f32x4*)(outf + base) = o;
  *(u16x4*)(outbf + base) = ob;
}

// ---------------------------------------------------------------- QKV (shared 64x64 weight per head)
__global__ __launch_bounds__(256) void qkv_kernel(const unsigned short* __restrict__ hbf,
    const float* __restrict__ wq, const float* __restrict__ wk, const float* __restrict__ wv,
    unsigned short* __restrict__ q, unsigned short* __restrict__ k, unsigned short* __restrict__ v) {
  __shared__ float Wt[3][64 * 65];            // transposed [d][e], pad 65: conflict-free
  int tid = threadIdx.x;
  for (int j = 0; j < 16; ++j) {
    int idx = tid + 256 * j; int e = idx >> 6, d = idx & 63;
    Wt[0][d * 65 + e] = wq[idx];
    Wt[1][d * 65 + e] = wk[idx];
    Wt[2][d * 65 + e] = wv[idx];
  }
  __syncthreads();
  int lane = tid & 63, w = tid >> 6;
  for (int it = 0; it < 8; ++it) {
    int th = blockIdx.x * 32 + w * 8 + it;    // token-head in [0, 32768)
    int t = th >> 4, hh = th & 15;
    size_t off = (size_t)t * 1024 + hh * 64;
    float xv = bf2f(hbf[off + lane]);
    float aq = 0.f, ak = 0.f, av = 0.f;
    for (int d = 0; d < 64; ++d) {
      float xd = __shfl(xv, d);
      aq = fmaf(Wt[0][d * 65 + lane], xd, aq);
      ak = fmaf(Wt[1][d * 65 + lane], xd, ak);
      av = fmaf(Wt[2][d * 65 + lane], xd, av);
    }
    q[off + lane] = f2bf(aq);
    k[off + lane] = f2bf(ak);
    v[off + lane] = f2bf(av);
  }
}

// ---------------------------------------------------------------- V transpose: [b,s,h,e] -> [b,h,e,s]
__global__ __launch_bounds__(256) void vtrans_kernel(const unsigned short* __restrict__ v,
                                                     unsigned short* __restrict__ vt) {
  __shared__ unsigned short T[64 * 72];
  int tid = threadIdx.x, st = blockIdx.x, bh = blockIdx.y;
  int b = bh >> 4, hh = bh & 15;
  for (int j = 0; j < 2; ++j) {
    int idx = tid + 256 * j; int s = idx >> 3, e0 = (idx & 7) * 8;
    u16x8 r = *(const u16x8*)(v + ((size_t)(b * 1024 + st * 64 + s) * 16 + hh) * 64 + e0);
    for (int i = 0; i < 8; ++i) T[(e0 + i) * 72 + s] = r[i];
  }
  __syncthreads();
  for (int j = 0; j < 2; ++j) {
    int idx = tid + 256 * j; int e = idx >> 3, s0 = (idx & 7) * 8;
    u16x8 r = *(const u16x8*)(&T[e * 72 + s0]);
    *(u16x8*)(vt + ((size_t)(b * 16 + hh) * 64 + e) * 1024 + st * 64 + s0) = r;
  }
}

// ---------------------------------------------------------------- flash attention, scale 1/sqrt(D)=1/32
__global__ __launch_bounds__(256, 2) void attn_kernel(const unsigned short* __restrict__ qb,
    const unsigned short* __restrict__ kb, const unsigned short* __restrict__ vtb,
    unsigned short* __restrict__ ob) {
  constexpr int P = 72;                       // padded LDS stride (bf16 elems), 144B: 2-way max
  __shared__ unsigned short Ks[64 * P], Vs[64 * P], Ps[4][16 * P];
  int tid = threadIdx.x, lane = tid & 63, w = tid >> 6;
  int l15 = lane & 15, lg = lane >> 4;
  int qt = blockIdx.x, bh = blockIdx.y, b = bh >> 4, hh = bh & 15;
  int q0 = qt * 64 + w * 16;
  const unsigned short* qrow = qb + ((size_t)(b * 1024 + q0 + l15) * 16 + hh) * 64 + lg * 8;
  bf16x8 qa0 = asbf(*(const u16x8*)qrow);
  bf16x8 qa1 = asbf(*(const u16x8*)(qrow + 32));
  float m_[4] = {-1e30f, -1e30f, -1e30f, -1e30f};
  float ls[4] = {0.f, 0.f, 0.f, 0.f};
  f32x4 oacc[4] = {};
  const float inv = 1.f / 32.f;
  for (int kt = 0; kt < 16; ++kt) {
    for (int j = 0; j < 2; ++j) {
      int idx = tid + 256 * j; int r = idx >> 3, c0 = (idx & 7) * 8;
      *(u16x8*)(&Ks[r * P + c0]) =
          *(const u16x8*)(kb + ((size_t)(b * 1024 + kt * 64 + r) * 16 + hh) * 64 + c0);
      *(u16x8*)(&Vs[r * P + c0]) =
          *(const u16x8*)(vtb + ((size_t)(b * 16 + hh) * 64 + r) * 1024 + kt * 64 + c0);
    }
    __syncthreads();
    f32x4 sf[4] = {};
    for (int n = 0; n < 4; ++n) {
      bf16x8 k0 = asbf(*(const u16x8*)(&Ks[(n * 16 + l15) * P + lg * 8]));
      bf16x8 k1 = asbf(*(const u16x8*)(&Ks[(n * 16 + l15) * P + 32 + lg * 8]));
      sf[n] = __builtin_amdgcn_mfma_f32_16x16x32_bf16(qa0, k0, sf[n], 0, 0, 0);
      sf[n] = __builtin_amdgcn_mfma_f32_16x16x32_bf16(qa1, k1, sf[n], 0, 0, 0);
    }
    for (int n = 0; n < 4; ++n) sf[n] *= inv;
    float mx[4], sc[4];
    for (int r = 0; r < 4; ++r) {
      float t0 = fmaxf(fmaxf(sf[0][r], sf[1][r]), fmaxf(sf[2][r], sf[3][r]));
      for (int msk = 1; msk < 16; msk <<= 1) t0 = fmaxf(t0, __shfl_xor(t0, msk));
      mx[r] = fmaxf(m_[r], t0);
      sc[r] = __expf(m_[r] - mx[r]);
      m_[r] = mx[r];
    }
    float rsum[4] = {0.f, 0.f, 0.f, 0.f};
    unsigned short pb[4][4];
    for (int n = 0; n < 4; ++n)
      for (int r = 0; r < 4; ++r) {
        float pv = __expf(sf[n][r] - mx[r]);
        rsum[r] += pv;
        pb[n][r] = f2bf(pv);
      }
    for (int r = 0; r < 4; ++r) {
      float t0 = rsum[r];
      for (int msk = 1; msk < 16; msk <<= 1) t0 += __shfl_xor(t0, msk);
      ls[r] = ls[r] * sc[r] + t0;
    }
    for (int n = 0; n < 4; ++n)
      for (int r = 0; r < 4; ++r) oacc[n][r] *= sc[r];
    unsigned short* pw = Ps[w];                // per-wave region: no barrier needed
    for (int n = 0; n < 4; ++n)
      for (int r = 0; r < 4; ++r)
        pw[(4 * lg + r) * P + n * 16 + l15] = pb[n][r];
    asm volatile("s_waitcnt lgkmcnt(0)" ::: "memory");
    bf16x8 pa0 = asbf(*(const u16x8*)(&pw[l15 * P + lg * 8]));
    bf16x8 pa1 = asbf(*(const u16x8*)(&pw[l15 * P + 32 + lg * 8]));
    for (int n = 0; n < 4; ++n) {
      bf16x8 v0 = asbf(*(const u16x8*)(&Vs[(n * 16 + l15) * P + lg * 8]));
      bf16x8 v1 = asbf(*(const u16x8*)(&Vs[(n * 16 + l15) * P + 32 + lg * 8]));
      oacc[n] = __builtin_amdgcn_mfma_f32_16x16x32_bf16(pa0, v0, oacc[n], 0, 0, 0);
      oacc[n] = __builtin_amdgcn_mfma_f32_16x16x32_bf16(pa1, v1, oacc[n], 0, 0, 0);
    }
    __syncthreads();
  }
  for (int n = 0; n < 4; ++n)
    for (int r = 0; r < 4; ++r) {
      float o = oacc[n][r] / ls[r];
      ob[((size_t)(b * 1024 + q0 + 4 * lg + r) * 16 + hh) * 64 + n * 16 + l15] = f2bf(o);
    }
}

// ---------------------------------------------------------------- generic GEMM: C = epi(A_bf16 @ B_f32^T + bias)
// A:[M,K] bf16 row-major; B:[N,K] f32 row-major; EPI 0: f32 out, 1: gelu -> bf16 out
template <int EPI>
__global__ __launch_bounds__(256, 2) void gemm_kernel(
    const unsigned short* __restrict__ A, const float* __restrict__ B,
    const float* __restrict__ bias, float* __restrict__ Cf, unsigned short* __restrict__ Cb,
    int M, int N, int K) {
  constexpr int BM = 128, BN = 128, BK = 32, LDP = 40;  // pad 40: 80B stride, 2-way max
  __shared__ unsigned short As[2][BM * LDP];
  __shared__ unsigned short Bs[2][BN * LDP];
  int tid = threadIdx.x, lane = tid & 63, w = tid >> 6;
  int wm = (w >> 1) * 64, wn = (w & 1) * 64;
  int l15 = lane & 15, lg = lane >> 4;
  int m0 = blockIdx.x * BM, n0 = blockIdx.y * BN;

  int srow = tid >> 2, sk = (tid & 3) * 8;
  const unsigned short* ap = A + (size_t)(m0 + srow) * K + sk;
  const float* bp = B + (size_t)(n0 + srow) * K + sk;
  int woff = srow * LDP + sk;

  f32x4 acc[4][4] = {};

  u16x8 a0 = *(const u16x8*)ap;
  u16x8 a1 = *(const u16x8*)(ap + (size_t)64 * K);
  f32x4 b00 = *(const f32x4*)bp;
  f32x4 b01 = *(const f32x4*)(bp + 4);
  f32x4 b10 = *(const f32x4*)(bp + (size_t)64 * K);
  f32x4 b11 = *(const f32x4*)(bp + (size_t)64 * K + 4);

  auto stage = [&](int buf, u16x8 va0, u16x8 va1, f32x4 vb00, f32x4 vb01, f32x4 vb10, f32x4 vb11) {
    *(u16x8*)(&As[buf][woff]) = va0;
    *(u16x8*)(&As[buf][woff + 64 * LDP]) = va1;
    u16x8 c0, c1;
    for (int i = 0; i < 4; ++i) {
      c0[i] = f2bf(vb00[i]); c0[i + 4] = f2bf(vb01[i]);
      c1[i] = f2bf(vb10[i]); c1[i + 4] = f2bf(vb11[i]);
    }
    *(u16x8*)(&Bs[buf][woff]) = c0;
    *(u16x8*)(&Bs[buf][woff + 64 * LDP]) = c1;
  };
  stage(0, a0, a1, b00, b01, b10, b11);
  __syncthreads();

  int nt = K / BK, cur = 0;
  for (int t = 0; t < nt; ++t) {
    u16x8 na0, na1; f32x4 nb00, nb01, nb10, nb11;
    if (t + 1 < nt) {                          // issue next-tile loads before compute (hide HBM)
      ap += BK; bp += BK;
      na0 = *(const u16x8*)ap;
      na1 = *(const u16x8*)(ap + (size_t)64 * K);
      nb00 = *(const f32x4*)bp;
      nb01 = *(const f32x4*)(bp + 4);
      nb10 = *(const f32x4*)(bp + (size_t)64 * K);
      nb11 = *(const f32x4*)(bp + (size_t)64 * K + 4);
    }
    const unsigned short* as = As[cur];
    const unsigned short* bs = Bs[cur];
    bf16x8 af[4], bfr[4];
    for (int mi = 0; mi < 4; ++mi)
      af[mi] = asbf(*(const u16x8*)(&as[(wm + mi * 16 + l15) * LDP + lg * 8]));
    for (int ni = 0; ni < 4; ++ni)
      bfr[ni] = asbf(*(const u16x8*)(&bs[(wn + ni * 16 + l15) * LDP + lg * 8]));
    for (int mi = 0; mi < 4; ++mi)
      for (int ni = 0; ni < 4; ++ni)
        acc[mi][ni] = __builtin_amdgcn_mfma_f32_16x16x32_bf16(af[mi], bfr[ni], acc[mi][ni], 0, 0, 0);
    if (t + 1 < nt) stage(cur ^ 1, na0, na1, nb00, nb01, nb10, nb11);
    __syncthreads();
    cur ^= 1;
  }

  for (int mi = 0; mi < 4; ++mi)
    for (int ni = 0; ni < 4; ++ni) {
      int col = n0 + wn + ni * 16 + l15;
      float bv = bias[col];
      for (int r = 0; r < 4; ++r) {
        int row = m0 + wm + mi * 16 + 4 * lg + r;
        float vv = acc[mi][ni][r] + bv;
        if constexpr (EPI == 1) {
          vv = 0.5f * vv * (1.f + erff(vv * 0.70710678118f));  // exact GELU
          Cb[(size_t)row * N + col] = f2bf(vv);
        } else {
          Cf[(size_t)row * N + col] = vv;
        }
      }
    }
}

// ----------------------------------------------------------------
extern "C" void kernel_launch(void* const* d_in, const int* in_sizes, int n_in,
                              void* d_out, int out_size, void* d_ws, size_t ws_size,
                              hipStream_t stream) {
  const int* x = (const int*)d_in[0];
  const float* tok = (const float*)d_in[1];
  const float* pos = (const float*)d_in[2];
  const float* wq = (const float*)d_in[3];
  const float* wk = (const float*)d_in[4];
  const float* wv = (const float*)d_in[5];
  const float* wo = (const float*)d_in[6];
  const float* bo = (const float*)d_in[7];
  const float* ln1g = (const float*)d_in[8];
  const float* ln1b = (const float*)d_in[9];
  const float* ln2g = (const float*)d_in[10];
  const float* ln2b = (const float*)d_in[11];
  const float* w1 = (const float*)d_in[12];
  const float* b1 = (const float*)d_in[13];
  const float* w2 = (const float*)d_in[14];
  const float* b2 = (const float*)d_in[15];
  const float* outw = (const float*)d_in[16];
  const float* outb = (const float*)d_in[17];
  float* out = (float*)d_out;

  char* p = (char*)d_ws;
  auto alloc = [&](size_t bytes) { char* r = p; p += (bytes + 255) & ~(size_t)255; return r; };
  const size_t TD = 2048ull * 1024;            // tokens x D
  float* hf = (float*)alloc(TD * 4);
  float* x1f = (float*)alloc(TD * 4);
  float* cf = (float*)alloc(TD * 4);
  unsigned short* hbf = (unsigned short*)alloc(TD * 2);
  unsigned short* x1bf = (unsigned short*)alloc(TD * 2);
  unsigned short* qkvr = (unsigned short*)alloc(4 * TD * 2);  // q|k|v|vt, reused as ffh
  unsigned short* qbf = qkvr;
  unsigned short* kbf = qkvr + TD;
  unsigned short* vbf = qkvr + 2 * TD;
  unsigned short* vtbf = qkvr + 3 * TD;
  unsigned short* aobf = vbf;                  // alias: v dead after vtrans
  unsigned short* ffbf = qkvr;                 // alias: q/k/v/vt dead after attention
  if ((size_t)(p - (char*)d_ws) > ws_size) return;  // ws too small -> fail loudly

  embed_kernel<<<2048, 256, 0, stream>>>(x, tok, pos, hf, hbf);
  for (int l = 0; l < 4; ++l) {
    qkv_kernel<<<1024, 256, 0, stream>>>(hbf, wq + l * 4096, wk + l * 4096, wv + l * 4096,
                                         qbf, kbf, vbf);
    vtrans_kernel<<<dim3(16, 32), 256, 0, stream>>>(vbf, vtbf);
    attn_kernel<<<dim3(16, 32), 256, 0, stream>>>(qbf, kbf, vtbf, aobf);
    gemm_kernel<0><<<dim3(16, 8), 256, 0, stream>>>(aobf, wo + (size_t)l * 1024 * 1024,
                                                    bo + l * 1024, cf, nullptr, 2048, 1024, 1024);
    ln_kernel<<<2048, 256, 0, stream>>>(cf, hf, ln1g + l * 1024, ln1b + l * 1024, x1f, x1bf);
    gemm_kernel<1><<<dim3(16, 32), 256, 0, stream>>>(x1bf, w1 + (size_t)l * 4096 * 1024,
                                                     b1 + l * 4096, nullptr, ffbf, 2048, 4096, 1024);
    gemm_kernel<0><<<dim3(16, 8), 256, 0, stream>>>(ffbf, w2 + (size_t)l * 1024 * 4096,
                                                    b2 + l * 1024, cf, nullptr, 2048, 1024, 4096);
    ln_kernel<<<2048, 256, 0, stream>>>(cf, x1f, ln2g + l * 1024, ln2b + l * 1024, hf, hbf);
  }
  gemm_kernel<0><<<dim3(16, 250), 256, 0, stream>>>(hbf, outw, outb, out, nullptr,
                                                    2048, 32000, 1024);
}

// Round 2
// 1177.530 us; speedup vs baseline: 2.2609x; 2.2609x over previous
//
#include <hip/hip_runtime.h>
#include <math.h>

typedef float f32x4 __attribute__((ext_vector_type(4)));
typedef unsigned short u16x8 __attribute__((ext_vector_type(8)));
typedef unsigned short u16x4 __attribute__((ext_vector_type(4)));
typedef __bf16 bf16x8 __attribute__((ext_vector_type(8)));
typedef unsigned int u32;

#define DEV static __device__ __forceinline__

DEV unsigned short f2bf(float f) {            // RNE f32 -> bf16 bits
  unsigned u = __float_as_uint(f);
  u += 0x7FFFu + ((u >> 16) & 1u);
  return (unsigned short)(u >> 16);
}
DEV float bf2f(unsigned short s) { return __uint_as_float(((unsigned)s) << 16); }
DEV bf16x8 asbf(u16x8 v) { return __builtin_bit_cast(bf16x8, v); }

DEV void gload16(const void* g, void* l) {    // async global->LDS, 16B/lane, wave-uniform LDS base
  __builtin_amdgcn_global_load_lds((const __attribute__((address_space(1))) u32*)g,
                                   (__attribute__((address_space(3))) u32*)l, 16, 0, 0);
}

// ---------------------------------------------------------------- f32 -> bf16 bulk convert
__global__ void cvt_kernel(const float* __restrict__ in, unsigned short* __restrict__ out, int n8) {
  for (int i = blockIdx.x * 256 + threadIdx.x; i < n8; i += gridDim.x * 256) {
    const float* s = in + (size_t)i * 8;
    f32x4 a = *(const f32x4*)s, b = *(const f32x4*)(s + 4);
    u16x8 o;
    for (int j = 0; j < 4; ++j) { o[j] = f2bf(a[j]); o[j + 4] = f2bf(b[j]); }
    *(u16x8*)(out + (size_t)i * 8) = o;
  }
}

// ---------------------------------------------------------------- embed
__global__ void embed_kernel(const int* __restrict__ x, const float* __restrict__ tok,
                             const float* __restrict__ pos, float* __restrict__ h,
                             unsigned short* __restrict__ hbf) {
  int t = blockIdx.x, tid = threadIdx.x;
  int v = x[t], s = t & 1023;                 // S = 1024
  f32x4 a = *(const f32x4*)(tok + (size_t)v * 1024 + tid * 4);
  f32x4 b = *(const f32x4*)(pos + (size_t)s * 1024 + tid * 4);
  f32x4 r = a + b;
  *(f32x4*)(h + (size_t)t * 1024 + tid * 4) = r;
  u16x4 rb;
  for (int i = 0; i < 4; ++i) rb[i] = f2bf(r[i]);
  *(u16x4*)(hbf + (size_t)t * 1024 + tid * 4) = rb;
}

// ---------------------------------------------------------------- LayerNorm(preA + preB + res)
__global__ __launch_bounds__(256) void ln_kernel(const float* __restrict__ preA,
    const float* __restrict__ preB, const float* __restrict__ res,
    const float* __restrict__ g, const float* __restrict__ bta,
    float* __restrict__ outf, unsigned short* __restrict__ outbf) {
  int row = blockIdx.x, tid = threadIdx.x;
  size_t base = (size_t)row * 1024 + tid * 4;
  f32x4 xv = *(const f32x4*)(preA + base);
  xv += *(const f32x4*)(preB + base);
  xv += *(const f32x4*)(res + base);
  float s = xv[0] + xv[1] + xv[2] + xv[3];
  float s2 = xv[0]*xv[0] + xv[1]*xv[1] + xv[2]*xv[2] + xv[3]*xv[3];
  for (int m = 1; m < 64; m <<= 1) { s += __shfl_xor(s, m); s2 += __shfl_xor(s2, m); }
  __shared__ float red[8];
  int w = tid >> 6;
  if ((tid & 63) == 0) { red[w * 2] = s; red[w * 2 + 1] = s2; }
  __syncthreads();
  s = red[0] + red[2] + red[4] + red[6];
  s2 = red[1] + red[3] + red[5] + red[7];
  float mu = s * (1.f / 1024.f);
  float var = s2 * (1.f / 1024.f) - mu * mu;
  float rs = rsqrtf(var + 1e-5f);
  f32x4 gv = *(const f32x4*)(g + tid * 4);
  f32x4 bv = *(const f32x4*)(bta + tid * 4);
  f32x4 o; u16x4 ob;
  for (int i = 0; i < 4; ++i) { o[i] = (xv[i] - mu) * rs * gv[i] + bv[i]; ob[i] = f2bf(o[i]); }
  *(f32x4*)(outf + base) = o;
  *(u16x4*)(outbf + base) = ob;
}

// ---------------------------------------------------------------- QKV (shared 64x64 weight per head)
__global__ __launch_bounds__(256) void qkv_kernel(const unsigned short* __restrict__ hbf,
    const float* __restrict__ wq, const float* __restrict__ wk, const float* __restrict__ wv,
    unsigned short* __restrict__ q, unsigned short* __restrict__ k, unsigned short* __restrict__ v) {
  __shared__ float Wt[3][64 * 65];            // transposed [d][e], pad 65: conflict-free
  int tid = threadIdx.x;
  for (int j = 0; j < 16; ++j) {
    int idx = tid + 256 * j; int e = idx >> 6, d = idx & 63;
    Wt[0][d * 65 + e] = wq[idx];
    Wt[1][d * 65 + e] = wk[idx];
    Wt[2][d * 65 + e] = wv[idx];
  }
  __syncthreads();
  int lane = tid & 63, w = tid >> 6;
  for (int it = 0; it < 8; ++it) {
    int th = blockIdx.x * 32 + w * 8 + it;    // token-head in [0, 32768)
    int t = th >> 4, hh = th & 15;
    size_t off = (size_t)t * 1024 + hh * 64;
    float xv = bf2f(hbf[off + lane]);
    float aq = 0.f, ak = 0.f, av = 0.f;
    for (int d = 0; d < 64; ++d) {
      float xd = __shfl(xv, d);
      aq = fmaf(Wt[0][d * 65 + lane], xd, aq);
      ak = fmaf(Wt[1][d * 65 + lane], xd, ak);
      av = fmaf(Wt[2][d * 65 + lane], xd, av);
    }
    q[off + lane] = f2bf(aq);
    k[off + lane] = f2bf(ak);
    v[off + lane] = f2bf(av);
  }
}

// ---------------------------------------------------------------- V transpose: [b,s,h,e] -> [b,h,e,s]
__global__ __launch_bounds__(256) void vtrans_kernel(const unsigned short* __restrict__ v,
                                                     unsigned short* __restrict__ vt) {
  __shared__ unsigned short T[64 * 72];
  int tid = threadIdx.x, st = blockIdx.x, bh = blockIdx.y;
  int b = bh >> 4, hh = bh & 15;
  for (int j = 0; j < 2; ++j) {
    int idx = tid + 256 * j; int s = idx >> 3, e0 = (idx & 7) * 8;
    u16x8 r = *(const u16x8*)(v + ((size_t)(b * 1024 + st * 64 + s) * 16 + hh) * 64 + e0);
    for (int i = 0; i < 8; ++i) T[(e0 + i) * 72 + s] = r[i];
  }
  __syncthreads();
  for (int j = 0; j < 2; ++j) {
    int idx = tid + 256 * j; int e = idx >> 3, s0 = (idx & 7) * 8;
    u16x8 r = *(const u16x8*)(&T[e * 72 + s0]);
    *(u16x8*)(vt + ((size_t)(b * 16 + hh) * 64 + e) * 1024 + st * 64 + s0) = r;
  }
}

// ---------------------------------------------------------------- flash attention, scale 1/sqrt(D)=1/32
__global__ __launch_bounds__(256, 2) void attn_kernel(const unsigned short* __restrict__ qb,
    const unsigned short* __restrict__ kb, const unsigned short* __restrict__ vtb,
    unsigned short* __restrict__ ob) {
  constexpr int P = 72;
  __shared__ unsigned short Ks[64 * P], Vs[64 * P], Ps[4][16 * P];
  int tid = threadIdx.x, lane = tid & 63, w = tid >> 6;
  int l15 = lane & 15, lg = lane >> 4;
  int qt = blockIdx.x, bh = blockIdx.y, b = bh >> 4, hh = bh & 15;
  int q0 = qt * 64 + w * 16;
  const unsigned short* qrow = qb + ((size_t)(b * 1024 + q0 + l15) * 16 + hh) * 64 + lg * 8;
  bf16x8 qa0 = asbf(*(const u16x8*)qrow);
  bf16x8 qa1 = asbf(*(const u16x8*)(qrow + 32));
  float m_[4] = {-1e30f, -1e30f, -1e30f, -1e30f};
  float ls[4] = {0.f, 0.f, 0.f, 0.f};
  f32x4 oacc[4] = {};
  const float inv = 1.f / 32.f;
  for (int kt = 0; kt < 16; ++kt) {
    for (int j = 0; j < 2; ++j) {
      int idx = tid + 256 * j; int r = idx >> 3, c0 = (idx & 7) * 8;
      *(u16x8*)(&Ks[r * P + c0]) =
          *(const u16x8*)(kb + ((size_t)(b * 1024 + kt * 64 + r) * 16 + hh) * 64 + c0);
      *(u16x8*)(&Vs[r * P + c0]) =
          *(const u16x8*)(vtb + ((size_t)(b * 16 + hh) * 64 + r) * 1024 + kt * 64 + c0);
    }
    __syncthreads();
    f32x4 sf[4] = {};
    for (int n = 0; n < 4; ++n) {
      bf16x8 k0 = asbf(*(const u16x8*)(&Ks[(n * 16 + l15) * P + lg * 8]));
      bf16x8 k1 = asbf(*(const u16x8*)(&Ks[(n * 16 + l15) * P + 32 + lg * 8]));
      sf[n] = __builtin_amdgcn_mfma_f32_16x16x32_bf16(qa0, k0, sf[n], 0, 0, 0);
      sf[n] = __builtin_amdgcn_mfma_f32_16x16x32_bf16(qa1, k1, sf[n], 0, 0, 0);
    }
    for (int n = 0; n < 4; ++n) sf[n] *= inv;
    float mx[4], sc[4];
    for (int r = 0; r < 4; ++r) {
      float t0 = fmaxf(fmaxf(sf[0][r], sf[1][r]), fmaxf(sf[2][r], sf[3][r]));
      for (int msk = 1; msk < 16; msk <<= 1) t0 = fmaxf(t0, __shfl_xor(t0, msk));
      mx[r] = fmaxf(m_[r], t0);
      sc[r] = __expf(m_[r] - mx[r]);
      m_[r] = mx[r];
    }
    float rsum[4] = {0.f, 0.f, 0.f, 0.f};
    unsigned short pb[4][4];
    for (int n = 0; n < 4; ++n)
      for (int r = 0; r < 4; ++r) {
        float pv = __expf(sf[n][r] - mx[r]);
        rsum[r] += pv;
        pb[n][r] = f2bf(pv);
      }
    for (int r = 0; r < 4; ++r) {
      float t0 = rsum[r];
      for (int msk = 1; msk < 16; msk <<= 1) t0 += __shfl_xor(t0, msk);
      ls[r] = ls[r] * sc[r] + t0;
    }
    for (int n = 0; n < 4; ++n)
      for (int r = 0; r < 4; ++r) oacc[n][r] *= sc[r];
    unsigned short* pw = Ps[w];
    for (int n = 0; n < 4; ++n)
      for (int r = 0; r < 4; ++r)
        pw[(4 * lg + r) * P + n * 16 + l15] = pb[n][r];
    asm volatile("s_waitcnt lgkmcnt(0)" ::: "memory");
    bf16x8 pa0 = asbf(*(const u16x8*)(&pw[l15 * P + lg * 8]));
    bf16x8 pa1 = asbf(*(const u16x8*)(&pw[l15 * P + 32 + lg * 8]));
    for (int n = 0; n < 4; ++n) {
      bf16x8 v0 = asbf(*(const u16x8*)(&Vs[(n * 16 + l15) * P + lg * 8]));
      bf16x8 v1 = asbf(*(const u16x8*)(&Vs[(n * 16 + l15) * P + 32 + lg * 8]));
      oacc[n] = __builtin_amdgcn_mfma_f32_16x16x32_bf16(pa0, v0, oacc[n], 0, 0, 0);
      oacc[n] = __builtin_amdgcn_mfma_f32_16x16x32_bf16(pa1, v1, oacc[n], 0, 0, 0);
    }
    __syncthreads();
  }
  for (int n = 0; n < 4; ++n)
    for (int r = 0; r < 4; ++r) {
      float o = oacc[n][r] / ls[r];
      ob[((size_t)(b * 1024 + q0 + 4 * lg + r) * 16 + hh) * 64 + n * 16 + l15] = f2bf(o);
    }
}

// ---------------------------------------------------------------- bf16 GEMM, m97 structure
// C = epi(A @ B^T + bias). A:[M,K] bf16, B:[N,K] bf16 (row-major), BN=128 fixed, BK=32.
// KSPLIT=2: grid covers 2 K-halves -> kh0 writes CfA(+bias), kh1 writes CfB.
// EPI 0: f32 out; EPI 1: exact-GELU -> bf16 out.
template <int BM, int KSPLIT, int EPI, bool SWZ>
__global__ __launch_bounds__(256) void gemm_kernel(
    const unsigned short* __restrict__ A, int lda,
    const unsigned short* __restrict__ B, int ldb,
    const float* __restrict__ bias,
    float* __restrict__ CfA, float* __restrict__ CfB, unsigned short* __restrict__ Cb,
    int ldc, int Ksub) {
  constexpr int LOGMT = (BM == 128) ? 4 : 5;  // M = 2048 always
  constexpr int MT = 2048 / BM;
  constexpr int MI = BM / 32;                 // A-frags per wave
  __shared__ alignas(16) char smem[33280];    // max(stage 32KB, Cs 64*130*4)
  unsigned short* As = (unsigned short*)smem;           // [2][BM*32]
  unsigned short* Bs = As + 2 * BM * 32;                // [2][128*32]
  float* Cs = (float*)smem;                             // epilogue bounce, stride 130

  int wg = blockIdx.x;
  if (SWZ) { int c = (int)gridDim.x >> 3; wg = (wg & 7) * c + (wg >> 3); }  // grid%8==0
  int mt = wg & (MT - 1);
  int rest = wg >> LOGMT;
  int nt, kh;
  if (KSPLIT == 2) { nt = rest & 7; kh = rest >> 3; }   // NT must be 8 when split
  else { nt = rest; kh = 0; }
  int m0 = mt * BM, n0 = nt * 128;
  const unsigned short* Ae = A + (KSPLIT == 2 ? (size_t)kh * Ksub : 0);
  const unsigned short* Be = B + (KSPLIT == 2 ? (size_t)kh * Ksub : 0);

  int tid = threadIdx.x, ln = tid & 63, wv = tid >> 6;
  int l15 = ln & 15, lg = ln >> 4;
  int wm = (wv >> 1) * (BM / 2), wn = (wv & 1) * 64;

  auto stage = [&](int buf, int k0) {
    for (int j = 0; j < BM / 64; ++j) {
      int row = j * 64 + wv * 16 + (ln >> 2);
      gload16(Ae + (size_t)(m0 + row) * lda + k0 + (ln & 3) * 8,
              &As[buf * (BM * 32) + (j * 64 + wv * 16) * 32]);
    }
    for (int j = 0; j < 2; ++j) {
      int row = j * 64 + wv * 16 + (ln >> 2);
      gload16(Be + (size_t)(n0 + row) * ldb + k0 + (ln & 3) * 8,
              &Bs[buf * 4096 + (j * 64 + wv * 16) * 32]);
    }
  };

  f32x4 acc[MI][4] = {};
  auto compute = [&](int buf) {
    const unsigned short* as = &As[buf * (BM * 32)];
    const unsigned short* bs = &Bs[buf * 4096];
    bf16x8 af[MI], bfn[4];
    for (int mi = 0; mi < MI; ++mi)
      af[mi] = asbf(*(const u16x8*)&as[(wm + mi * 16 + l15) * 32 + lg * 8]);
    for (int ni = 0; ni < 4; ++ni)
      bfn[ni] = asbf(*(const u16x8*)&bs[(wn + ni * 16 + l15) * 32 + lg * 8]);
    for (int mi = 0; mi < MI; ++mi)
      for (int ni = 0; ni < 4; ++ni)
        acc[mi][ni] = __builtin_amdgcn_mfma_f32_16x16x32_bf16(af[mi], bfn[ni], acc[mi][ni], 0, 0, 0);
  };

  stage(0, 0);
  __syncthreads();
  int ntk = Ksub >> 5, cur = 0;
  for (int t = 0; t < ntk - 1; ++t) {
    stage(cur ^ 1, (t + 1) << 5);   // async loads for next tile, in flight across compute
    compute(cur);
    __syncthreads();                // drains vmcnt(0): next tile staged
    cur ^= 1;
  }
  compute(cur);

  // ---- epilogue: bounce through LDS for full-line coalesced stores
  float* Cf = (kh == 0) ? CfA : CfB;
  const bool addb = (kh == 0);
  for (int p = 0; p < BM / 64; ++p) {
    __syncthreads();
    if ((wm >> 6) == p) {
      int rb = wm & 63;
      for (int mi = 0; mi < MI; ++mi)
        for (int ni = 0; ni < 4; ++ni) {
          int cn = wn + ni * 16 + l15;
          float bv = addb ? bias[n0 + cn] : 0.f;
          for (int r = 0; r < 4; ++r) {
            float vv = acc[mi][ni][r] + bv;
            if (EPI == 1) vv = 0.5f * vv * (1.f + erff(vv * 0.70710678118f));
            Cs[(rb + mi * 16 + 4 * lg + r) * 130 + cn] = vv;
          }
        }
    }
    __syncthreads();
    int row = tid >> 3;
    for (int ri = 0; ri < 2; ++ri) {
      int lr = ri * 32 + row;
      size_t gbase = (size_t)(m0 + p * 64 + lr) * ldc + n0;
      if (EPI == 0) {
        int c4 = (tid & 7) * 4;
        for (int j = 0; j < 4; ++j)
          *(f32x4*)(Cf + gbase + c4 + j * 32) = *(const f32x4*)&Cs[lr * 130 + c4 + j * 32];
      } else {
        for (int j = 0; j < 2; ++j) {
          int cc = (tid & 7) * 8 + j * 64;
          f32x4 v0 = *(const f32x4*)&Cs[lr * 130 + cc];
          f32x4 v1 = *(const f32x4*)&Cs[lr * 130 + cc + 4];
          u16x8 o;
          for (int i = 0; i < 4; ++i) { o[i] = f2bf(v0[i]); o[i + 4] = f2bf(v1[i]); }
          *(u16x8*)(Cb + gbase + cc) = o;
        }
      }
    }
  }
}

// ----------------------------------------------------------------
extern "C" void kernel_launch(void* const* d_in, const int* in_sizes, int n_in,
                              void* d_out, int out_size, void* d_ws, size_t ws_size,
                              hipStream_t stream) {
  const int* x = (const int*)d_in[0];
  const float* tok = (const float*)d_in[1];
  const float* pos = (const float*)d_in[2];
  const float* wq = (const float*)d_in[3];
  const float* wk = (const float*)d_in[4];
  const float* wv = (const float*)d_in[5];
  const float* wo = (const float*)d_in[6];
  const float* bo = (const float*)d_in[7];
  const float* ln1g = (const float*)d_in[8];
  const float* ln1b = (const float*)d_in[9];
  const float* ln2g = (const float*)d_in[10];
  const float* ln2b = (const float*)d_in[11];
  const float* w1 = (const float*)d_in[12];
  const float* b1 = (const float*)d_in[13];
  const float* w2 = (const float*)d_in[14];
  const float* b2 = (const float*)d_in[15];
  const float* outw = (const float*)d_in[16];
  const float* outb = (const float*)d_in[17];
  float* out = (float*)d_out;

  // ---- workspace layout (peak ~70 MB; outwbf overlaps all dead layer buffers)
  const size_t MiB = 1 << 20;
  const size_t need = 4 * MiB + 65536000;     // hbf + REGION(outwbf)
  if (ws_size < need) return;                 // fail loudly if ws too small
  char* base = (char*)d_ws;
  unsigned short* hbf = (unsigned short*)base;            // 4 MiB, persistent
  char* R = base + 4 * MiB;                               // REGION
  float* hf  = (float*)(R);                               // 8 MiB
  float* x1f = (float*)(R + 8 * MiB);                     // 8 MiB
  unsigned short* x1bf = (unsigned short*)(R + 16 * MiB); // 4 MiB
  float* cfA = (float*)(R + 20 * MiB);                    // 8 MiB
  float* cfB = (float*)(R + 28 * MiB);                    // 8 MiB
  unsigned short* qs = (unsigned short*)(R + 36 * MiB);   // 6 slots x 4 MiB
  const size_t SL = 2048ull * 1024;                       // slot elems (u16)
  unsigned short* qbf = qs;
  unsigned short* kbf = qs + SL;
  unsigned short* vbf = qs + 2 * SL;                      // also attn-out
  unsigned short* vtbf = qs + 3 * SL;                     // also wobf
  unsigned short* wobf = vtbf;
  unsigned short* w1bf = qbf;                             // q+k slots (8 MiB)
  unsigned short* w2bf = qbf;
  unsigned short* ffbf = vbf;                             // v..e2 slots (16 MiB)
  unsigned short* outwbf = (unsigned short*)R;            // 62.5 MiB, after layers

  embed_kernel<<<2048, 256, 0, stream>>>(x, tok, pos, hf, hbf);
  for (int l = 0; l < 4; ++l) {
    qkv_kernel<<<1024, 256, 0, stream>>>(hbf, wq + l * 4096, wk + l * 4096, wv + l * 4096,
                                         qbf, kbf, vbf);
    vtrans_kernel<<<dim3(16, 32), 256, 0, stream>>>(vbf, vtbf);
    attn_kernel<<<dim3(16, 32), 256, 0, stream>>>(qbf, kbf, vtbf, vbf);
    cvt_kernel<<<512, 256, 0, stream>>>(wo + (size_t)l * 1048576, wobf, 131072);
    cvt_kernel<<<2048, 256, 0, stream>>>(w1 + (size_t)l * 4194304, w1bf, 524288);
    gemm_kernel<64, 2, 0, false><<<512, 256, 0, stream>>>(
        vbf, 1024, wobf, 1024, bo + l * 1024, cfA, cfB, nullptr, 1024, 512);
    ln_kernel<<<2048, 256, 0, stream>>>(cfA, cfB, hf, ln1g + l * 1024, ln1b + l * 1024,
                                        x1f, x1bf);
    gemm_kernel<128, 1, 1, false><<<512, 256, 0, stream>>>(
        x1bf, 1024, w1bf, 1024, b1 + l * 4096, nullptr, nullptr, ffbf, 4096, 1024);
    cvt_kernel<<<2048, 256, 0, stream>>>(w2 + (size_t)l * 4194304, w2bf, 524288);
    gemm_kernel<64, 2, 0, false><<<512, 256, 0, stream>>>(
        ffbf, 4096, w2bf, 4096, b2 + l * 1024, cfA, cfB, nullptr, 1024, 2048);
    ln_kernel<<<2048, 256, 0, stream>>>(cfA, cfB, x1f, ln2g + l * 1024, ln2b + l * 1024,
                                        hf, hbf);
  }
  cvt_kernel<<<2048, 256, 0, stream>>>(outw, outwbf, 4096000);
  gemm_kernel<128, 1, 0, true><<<4000, 256, 0, stream>>>(
      hbf, 1024, outwbf, 1024, outb, out, nullptr, nullptr, 32000, 1024);
}